// Round 1
// baseline (686.586 us; speedup 1.0000x reference)
//
#include <hip/hip_runtime.h>
#include <cstdint>
#include <cstddef>

#define EPSV 1e-5f
#define TEMP_MINV 0.01f

// ---------------- flags: flags[l]=1 means residual entering level l is ~0 ----------------
// r_{l+1} = r_l - (r_l*s_l)/s_l  == 0 exactly when s_l == 1.0f (and stays 0 afterwards).
__global__ void flags_kernel(const float* __restrict__ scales, int L, int* __restrict__ flags) {
    if (threadIdx.x == 0 && blockIdx.x == 0) {
        int zero = 0;
        for (int l = 0; l < L; ++l) {
            flags[l] = zero;
            if (scales[l] == 1.0f) zero = 1;
        }
    }
}

// ---------------- GEMM1: Y[M,N] = A[M,Kd] @ Bm[N,Kd]^T + bias[N] ----------------
__global__ __launch_bounds__(256) void gemm_abt_bias(
    const float* __restrict__ A, const float* __restrict__ Bm,
    const float* __restrict__ bias, float* __restrict__ Y,
    int M, int N, int Kd) {
    __shared__ __align__(16) float As[16][68];   // [k][m], pad 68 -> <=2-way bank aliasing
    __shared__ __align__(16) float Bs[16][68];
    const int tid = threadIdx.x;
    const int tx = tid & 15, ty = tid >> 4;
    const int row0 = blockIdx.x * 64, col0 = blockIdx.y * 64;
    const int lr = tid >> 2, lc = (tid & 3) << 2;
    float acc[4][4] = {};
    for (int k0 = 0; k0 < Kd; k0 += 16) {
        float4 av = *(const float4*)(A  + (size_t)(row0 + lr) * Kd + k0 + lc);
        float4 bv = *(const float4*)(Bm + (size_t)(col0 + lr) * Kd + k0 + lc);
        __syncthreads();
        As[lc+0][lr]=av.x; As[lc+1][lr]=av.y; As[lc+2][lr]=av.z; As[lc+3][lr]=av.w;
        Bs[lc+0][lr]=bv.x; Bs[lc+1][lr]=bv.y; Bs[lc+2][lr]=bv.z; Bs[lc+3][lr]=bv.w;
        __syncthreads();
        #pragma unroll
        for (int kk = 0; kk < 16; ++kk) {
            const float4 a = *(const float4*)&As[kk][ty << 2];
            const float4 b = *(const float4*)&Bs[kk][tx << 2];
            acc[0][0] += a.x*b.x; acc[0][1] += a.x*b.y; acc[0][2] += a.x*b.z; acc[0][3] += a.x*b.w;
            acc[1][0] += a.y*b.x; acc[1][1] += a.y*b.y; acc[1][2] += a.y*b.z; acc[1][3] += a.y*b.w;
            acc[2][0] += a.z*b.x; acc[2][1] += a.z*b.y; acc[2][2] += a.z*b.z; acc[2][3] += a.z*b.w;
            acc[3][0] += a.w*b.x; acc[3][1] += a.w*b.y; acc[3][2] += a.w*b.z; acc[3][3] += a.w*b.w;
        }
    }
    #pragma unroll
    for (int i = 0; i < 4; ++i) {
        const int r = row0 + (ty << 2) + i;
        const int c = col0 + (tx << 2);
        float4 bb = *(const float4*)(bias + c);
        float4 o = make_float4(acc[i][0]+bb.x, acc[i][1]+bb.y, acc[i][2]+bb.z, acc[i][3]+bb.w);
        *(float4*)(Y + (size_t)r * N + c) = o;
    }
}

// ---------------- distance GEMM + logits epilogue ----------------
// out[r, l, c] = -(rsn[r] + cn[c] - 2 * dot(RS[r], CB[c])) / temp ; flagged: rsn=dot=0
__global__ __launch_bounds__(256) void dist_kernel(
    const float* __restrict__ RS, const float* __restrict__ CB,
    const float* __restrict__ rsn, const float* __restrict__ cn,
    const float* __restrict__ temp_p, const int* __restrict__ flags, int l,
    float* __restrict__ out, int M, int Kc, int Kd, int LK) {
    const float temp = fmaxf(temp_p[0], TEMP_MINV);
    const float inv_t = 1.0f / temp;
    const int flag = flags[l];
    __shared__ __align__(16) float As[16][68];
    __shared__ __align__(16) float Bs[16][68];
    const int tid = threadIdx.x;
    const int tx = tid & 15, ty = tid >> 4;
    const int row0 = blockIdx.x * 64, col0 = blockIdx.y * 64;
    float acc[4][4] = {};
    if (!flag) {
        const int lr = tid >> 2, lc = (tid & 3) << 2;
        for (int k0 = 0; k0 < Kd; k0 += 16) {
            float4 av = *(const float4*)(RS + (size_t)(row0 + lr) * Kd + k0 + lc);
            float4 bv = *(const float4*)(CB + (size_t)(col0 + lr) * Kd + k0 + lc);
            __syncthreads();
            As[lc+0][lr]=av.x; As[lc+1][lr]=av.y; As[lc+2][lr]=av.z; As[lc+3][lr]=av.w;
            Bs[lc+0][lr]=bv.x; Bs[lc+1][lr]=bv.y; Bs[lc+2][lr]=bv.z; Bs[lc+3][lr]=bv.w;
            __syncthreads();
            #pragma unroll
            for (int kk = 0; kk < 16; ++kk) {
                const float4 a = *(const float4*)&As[kk][ty << 2];
                const float4 b = *(const float4*)&Bs[kk][tx << 2];
                acc[0][0] += a.x*b.x; acc[0][1] += a.x*b.y; acc[0][2] += a.x*b.z; acc[0][3] += a.x*b.w;
                acc[1][0] += a.y*b.x; acc[1][1] += a.y*b.y; acc[1][2] += a.y*b.z; acc[1][3] += a.y*b.w;
                acc[2][0] += a.z*b.x; acc[2][1] += a.z*b.y; acc[2][2] += a.z*b.z; acc[2][3] += a.z*b.w;
                acc[3][0] += a.w*b.x; acc[3][1] += a.w*b.y; acc[3][2] += a.w*b.z; acc[3][3] += a.w*b.w;
            }
        }
    }
    #pragma unroll
    for (int i = 0; i < 4; ++i) {
        const int r = row0 + (ty << 2) + i;
        const int c = col0 + (tx << 2);
        const float rn = flag ? 0.0f : rsn[r];
        float4 cnv = *(const float4*)(cn + c);
        float4 o;
        o.x = -(rn + cnv.x - 2.0f * acc[i][0]) * inv_t;
        o.y = -(rn + cnv.y - 2.0f * acc[i][1]) * inv_t;
        o.z = -(rn + cnv.z - 2.0f * acc[i][2]) * inv_t;
        o.w = -(rn + cnv.w - 2.0f * acc[i][3]) * inv_t;
        *(float4*)(out + (size_t)r * LK + (size_t)l * Kc + c) = o;
    }
}

// ---------------- LayerNorm (one 256-thread block per row of Dd) ----------------
__global__ __launch_bounds__(256) void ln_kernel(
    const float* __restrict__ X, float* __restrict__ Y,
    const float* __restrict__ g, const float* __restrict__ b,
    int Dd, int affine_relu) {
    const int row = blockIdx.x;
    const float* p = X + (size_t)row * Dd;
    float* q = Y + (size_t)row * Dd;
    __shared__ float red[4];
    const int lane = threadIdx.x & 63, wv = threadIdx.x >> 6;
    float lsum = 0.f;
    for (int j = threadIdx.x; j < Dd; j += 256) lsum += p[j];
    for (int off = 32; off; off >>= 1) lsum += __shfl_down(lsum, off);
    if (lane == 0) red[wv] = lsum;
    __syncthreads();
    const float mu = (red[0] + red[1] + red[2] + red[3]) / (float)Dd;
    __syncthreads();
    float lvar = 0.f;
    for (int j = threadIdx.x; j < Dd; j += 256) { float d = p[j] - mu; lvar += d * d; }
    for (int off = 32; off; off >>= 1) lvar += __shfl_down(lvar, off);
    if (lane == 0) red[wv] = lvar;
    __syncthreads();
    const float inv = rsqrtf((red[0] + red[1] + red[2] + red[3]) / (float)Dd + EPSV);
    for (int j = threadIdx.x; j < Dd; j += 256) {
        float xn = (p[j] - mu) * inv;
        if (affine_relu) xn = fmaxf(xn * g[j] + b[j], 0.0f);
        q[j] = xn;
    }
}

// ---------------- row squared norms (one wave per row) ----------------
__global__ __launch_bounds__(256) void rownorm_kernel(
    const float* __restrict__ X, float* __restrict__ out,
    int rows, int Dd, const int* __restrict__ flags, int l) {
    if (flags && flags[l]) return;
    const int wv = threadIdx.x >> 6, lane = threadIdx.x & 63;
    const int row = blockIdx.x * 4 + wv;
    if (row >= rows) return;
    const float* p = X + (size_t)row * Dd;
    float s = 0.f;
    for (int j = lane; j < Dd; j += 64) { float v = p[j]; s += v * v; }
    for (int off = 32; off; off >>= 1) s += __shfl_down(s, off);
    if (lane == 0) out[row] = s;
}

// ---------------- rs_l = scale_l * (recurrence applied to x) ----------------
__global__ void rs_kernel(const float* __restrict__ X, const float* __restrict__ scales,
                          const int* __restrict__ flags, int l, float* __restrict__ RS, int n) {
    if (flags[l]) return;
    const int i = blockIdx.x * 256 + threadIdx.x;
    if (i >= n) return;
    float r = X[i];
    for (int j = 0; j < l; ++j) { float s = scales[j]; float rsv = r * s; r = r - rsv / s; }
    RS[i] = r * scales[l];
}

// ---------------- qsum = sum_l rs_l (elementwise, general recurrence) ----------------
__global__ void qsum_kernel(const float* __restrict__ X, const float* __restrict__ scales,
                            int L, float* __restrict__ Q, int n) {
    const int i = blockIdx.x * 256 + threadIdx.x;
    if (i >= n) return;
    float r = X[i], q = 0.f;
    for (int l = 0; l < L; ++l) {
        float s = scales[l];
        float rsv = r * s;
        q += rsv;
        r = r - rsv / s;
    }
    Q[i] = q;
}

extern "C" void kernel_launch(void* const* d_in, const int* in_sizes, int n_in,
                              void* d_out, int out_size, void* d_ws, size_t ws_size,
                              hipStream_t stream) {
    const float* features = (const float*)d_in[0];
    const float* W        = (const float*)d_in[1];
    const float* bproj    = (const float*)d_in[2];
    const float* lng      = (const float*)d_in[3];
    const float* lnb      = (const float*)d_in[4];
    const float* cb       = (const float*)d_in[5];
    const float* scales   = (const float*)d_in[6];
    const float* temp     = (const float*)d_in[7];

    const int D = in_sizes[2];            // 512
    const int M = in_sizes[0] / D;        // 8192
    const int L = in_sizes[6];            // 4
    const int K = in_sizes[5] / (L * D);  // 2048

    float* out    = (float*)d_out;                       // [M, L, K] logits
    float* out_ln = out + (size_t)M * L * K;             // [M, D] LN(qsum)

    // workspace layout (floats): x[M*D] | qs[M*D] | rs[M*D] | rsn[M] | cn[L*K] | flags[L]
    float* ws  = (float*)d_ws;
    float* x   = ws;
    float* qs  = x  + (size_t)M * D;
    float* rs  = qs + (size_t)M * D;
    float* rsn = rs + (size_t)M * D;
    float* cn  = rsn + M;
    int*   flags = (int*)(cn + (size_t)L * K);

    flags_kernel<<<1, 64, 0, stream>>>(scales, L, flags);

    // x = relu(LN(features @ W^T + bproj) * g + b)
    dim3 g1(M / 64, D / 64);
    gemm_abt_bias<<<g1, 256, 0, stream>>>(features, W, bproj, x, M, D, D);
    ln_kernel<<<M, 256, 0, stream>>>(x, x, lng, lnb, D, 1);

    // quantized_sum = LN(sum_l rs_l)  (no affine)
    qsum_kernel<<<(M * D + 255) / 256, 256, 0, stream>>>(x, scales, L, qs, M * D);
    ln_kernel<<<M, 256, 0, stream>>>(qs, out_ln, nullptr, nullptr, D, 0);

    // codebook row norms  cn[l*K + k] = ||cb_{l,k}||^2
    rownorm_kernel<<<(L * K + 3) / 4, 256, 0, stream>>>(cb, cn, L * K, D, nullptr, 0);

    // per-level logits
    dim3 gd(M / 64, K / 64);
    for (int l = 0; l < L; ++l) {
        rs_kernel<<<(M * D + 255) / 256, 256, 0, stream>>>(x, scales, flags, l, rs, M * D);
        rownorm_kernel<<<(M + 3) / 4, 256, 0, stream>>>(rs, rsn, M, D, flags, l);
        dist_kernel<<<gd, 256, 0, stream>>>(rs, cb + (size_t)l * K * D, rsn, cn + (size_t)l * K,
                                            temp, flags, l, out, M, K, D, L * K);
    }
}

// Round 2
// 442.576 us; speedup vs baseline: 1.5513x; 1.5513x over previous
//
#include <hip/hip_runtime.h>
#include <cstdint>
#include <cstddef>

#define EPSV 1e-5f
#define TEMP_MINV 0.01f

typedef __attribute__((ext_vector_type(8))) short bf16x8;
typedef __attribute__((ext_vector_type(4))) float f32x4;

__device__ inline short f2bf(float f) {
    unsigned u = __float_as_uint(f);
    unsigned r = (u + 0x7fffu + ((u >> 16) & 1u)) >> 16;
    return (short)r;
}

__device__ inline void gload16(const void* g, void* l) {
    __builtin_amdgcn_global_load_lds(
        (const __attribute__((address_space(1))) void*)g,
        (__attribute__((address_space(3))) void*)l, 16, 0, 0);
}

// ---------------- flags: flags[l]=1 means residual entering level l is 0 ----------------
__global__ void flags_kernel(const float* __restrict__ scales, int L, int* __restrict__ flags) {
    if (threadIdx.x == 0 && blockIdx.x == 0) {
        int zero = 0;
        for (int l = 0; l < L; ++l) {
            flags[l] = zero;
            if (scales[l] == 1.0f) zero = 1;
        }
    }
}

// ---------------- pack: fp32 [R][512] -> bf16 packed [64][R][8] ----------------
// mode 1: apply residual recurrence through level l then scale by scales[l].
__global__ __launch_bounds__(256) void pack_kernel(
    const float* __restrict__ in, short* __restrict__ outp, int R,
    const float* __restrict__ scales, const int* __restrict__ flags, int l, int mode) {
    if (flags && flags[l]) return;
    __shared__ __align__(16) short lds[32 * 520];   // row stride 520 shorts (1040 B)
    const int t = threadIdx.x;
    const int rb = blockIdx.x * 32;
    float s_arr[8];
    if (mode) {
        for (int j = 0; j <= l; ++j) s_arr[j] = scales[j];
    }
    const float4* in4 = (const float4*)(in + (size_t)rb * 512);
    #pragma unroll
    for (int it = 0; it < 16; ++it) {
        const int flat = it * 1024 + t * 4;
        float4 v = in4[flat >> 2];
        float e[4] = {v.x, v.y, v.z, v.w};
        if (mode) {
            #pragma unroll
            for (int q = 0; q < 4; ++q) {
                float r_ = e[q];
                for (int j = 0; j < l; ++j) { float sc = s_arr[j]; float rv = r_ * sc; r_ = r_ - rv / sc; }
                e[q] = r_ * s_arr[l];
            }
        }
        const int row = flat >> 9, col = flat & 511;
        short4 o; o.x = f2bf(e[0]); o.y = f2bf(e[1]); o.z = f2bf(e[2]); o.w = f2bf(e[3]);
        *(short4*)&lds[row * 520 + col] = o;
    }
    __syncthreads();
    #pragma unroll
    for (int it = 0; it < 8; ++it) {
        const int c = it * 256 + t;
        const int kb = c >> 5, r = c & 31;
        int4 v = *(const int4*)&lds[r * 520 + kb * 8];
        *(int4*)(outp + ((size_t)kb * R + rb + r) * 8) = v;
    }
}

// ---------------- GEMM1 (MFMA): y[M,N] = A[M,Kd] @ W[N,Kd]^T + bias, packed bf16 in ----------------
__global__ __launch_bounds__(256) void gemm1_mfma(
    const short* __restrict__ Ap, const short* __restrict__ Bp,
    const float* __restrict__ bias, float* __restrict__ Y,
    int M, int N, int Kd) {
    __shared__ __align__(16) short As[8 * 128 * 8];
    __shared__ __align__(16) short Bs[8 * 128 * 8];
    const int r0 = blockIdx.x * 128, c0 = blockIdx.y * 128;
    const int lane = threadIdx.x & 63, w = threadIdx.x >> 6;
    const int wm = (w & 1) << 6, wn = (w >> 1) << 6;
    const int fr = lane & 15, fo = lane >> 4;
    f32x4 acc[4][4];
    #pragma unroll
    for (int a = 0; a < 4; ++a)
        #pragma unroll
        for (int b = 0; b < 4; ++b) acc[a][b] = (f32x4){0.f, 0.f, 0.f, 0.f};
    for (int k0 = 0; k0 < Kd; k0 += 64) {
        const int kb0 = k0 >> 3;
        __syncthreads();
        #pragma unroll
        for (int sidx = 0; sidx < 2; ++sidx) {
            const int kblk = (w << 1) + sidx;
            const short* ga = Ap + ((size_t)(kb0 + kblk) * M + r0) * 8;
            const short* gb = Bp + ((size_t)(kb0 + kblk) * N + c0) * 8;
            short* la = &As[kblk * 128 * 8];
            short* lb = &Bs[kblk * 128 * 8];
            #pragma unroll
            for (int h = 0; h < 2; ++h) {
                gload16(ga + ((h << 6) + lane) * 8, la + (h << 6) * 8);
                gload16(gb + ((h << 6) + lane) * 8, lb + (h << 6) * 8);
            }
        }
        __syncthreads();
        #pragma unroll
        for (int s = 0; s < 2; ++s) {
            const int kb = (s << 2) + fo;
            bf16x8 af[4], bfv[4];
            #pragma unroll
            for (int mt = 0; mt < 4; ++mt)
                af[mt] = *(const bf16x8*)&As[(kb * 128 + wm + mt * 16 + fr) * 8];
            #pragma unroll
            for (int nt = 0; nt < 4; ++nt)
                bfv[nt] = *(const bf16x8*)&Bs[(kb * 128 + wn + nt * 16 + fr) * 8];
            #pragma unroll
            for (int mt = 0; mt < 4; ++mt)
                #pragma unroll
                for (int nt = 0; nt < 4; ++nt)
                    acc[mt][nt] = __builtin_amdgcn_mfma_f32_16x16x32_bf16(af[mt], bfv[nt], acc[mt][nt], 0, 0, 0);
        }
    }
    #pragma unroll
    for (int mt = 0; mt < 4; ++mt) {
        #pragma unroll
        for (int reg = 0; reg < 4; ++reg) {
            const int r = r0 + wm + mt * 16 + (fo << 2) + reg;
            float* orow = Y + (size_t)r * N;
            #pragma unroll
            for (int nt = 0; nt < 4; ++nt) {
                const int c = c0 + wn + nt * 16 + fr;
                orow[c] = acc[mt][nt][reg] + bias[c];
            }
        }
    }
}

// ---------------- dist (MFMA): out[r, l*Kc + c] = -(rsn[r]+cn[c]-2*dot)/temp ----------------
// flagged level: rs==0 -> broadcast -cn/temp.
__global__ __launch_bounds__(256) void dist_mfma(
    const short* __restrict__ Ap, const short* __restrict__ Bp,
    const float* __restrict__ rsn, const float* __restrict__ cnl,
    const float* __restrict__ temp_p, const int* __restrict__ flags, int l,
    float* __restrict__ outl, int M, int Kc, int Kd, int LK) {
    const float inv_t = 1.0f / fmaxf(temp_p[0], TEMP_MINV);
    const int r0 = blockIdx.x * 128, c0 = blockIdx.y * 128;
    if (flags[l]) {
        const int tc = (threadIdx.x & 31) << 2, tr = threadIdx.x >> 5;
        float4 cv = *(const float4*)(cnl + c0 + tc);
        float4 v = make_float4(-cv.x * inv_t, -cv.y * inv_t, -cv.z * inv_t, -cv.w * inv_t);
        #pragma unroll
        for (int i = 0; i < 16; ++i) {
            const int r = r0 + i * 8 + tr;
            *(float4*)(outl + (size_t)r * LK + c0 + tc) = v;
        }
        return;
    }
    __shared__ __align__(16) short As[8 * 128 * 8];
    __shared__ __align__(16) short Bs[8 * 128 * 8];
    const int lane = threadIdx.x & 63, w = threadIdx.x >> 6;
    const int wm = (w & 1) << 6, wn = (w >> 1) << 6;
    const int fr = lane & 15, fo = lane >> 4;
    f32x4 acc[4][4];
    #pragma unroll
    for (int a = 0; a < 4; ++a)
        #pragma unroll
        for (int b = 0; b < 4; ++b) acc[a][b] = (f32x4){0.f, 0.f, 0.f, 0.f};
    for (int k0 = 0; k0 < Kd; k0 += 64) {
        const int kb0 = k0 >> 3;
        __syncthreads();
        #pragma unroll
        for (int sidx = 0; sidx < 2; ++sidx) {
            const int kblk = (w << 1) + sidx;
            const short* ga = Ap + ((size_t)(kb0 + kblk) * M + r0) * 8;
            const short* gb = Bp + ((size_t)(kb0 + kblk) * Kc + c0) * 8;
            short* la = &As[kblk * 128 * 8];
            short* lb = &Bs[kblk * 128 * 8];
            #pragma unroll
            for (int h = 0; h < 2; ++h) {
                gload16(ga + ((h << 6) + lane) * 8, la + (h << 6) * 8);
                gload16(gb + ((h << 6) + lane) * 8, lb + (h << 6) * 8);
            }
        }
        __syncthreads();
        #pragma unroll
        for (int s = 0; s < 2; ++s) {
            const int kb = (s << 2) + fo;
            bf16x8 af[4], bfv[4];
            #pragma unroll
            for (int mt = 0; mt < 4; ++mt)
                af[mt] = *(const bf16x8*)&As[(kb * 128 + wm + mt * 16 + fr) * 8];
            #pragma unroll
            for (int nt = 0; nt < 4; ++nt)
                bfv[nt] = *(const bf16x8*)&Bs[(kb * 128 + wn + nt * 16 + fr) * 8];
            #pragma unroll
            for (int mt = 0; mt < 4; ++mt)
                #pragma unroll
                for (int nt = 0; nt < 4; ++nt)
                    acc[mt][nt] = __builtin_amdgcn_mfma_f32_16x16x32_bf16(af[mt], bfv[nt], acc[mt][nt], 0, 0, 0);
        }
    }
    #pragma unroll
    for (int mt = 0; mt < 4; ++mt) {
        #pragma unroll
        for (int reg = 0; reg < 4; ++reg) {
            const int r = r0 + wm + mt * 16 + (fo << 2) + reg;
            const float rn = rsn[r];
            float* orow = outl + (size_t)r * LK;
            #pragma unroll
            for (int nt = 0; nt < 4; ++nt) {
                const int c = c0 + wn + nt * 16 + fr;
                orow[c] = -(rn + cnl[c] - 2.0f * acc[mt][nt][reg]) * inv_t;
            }
        }
    }
}

// ---------------- LayerNorm (one 256-thread block per row) ----------------
__global__ __launch_bounds__(256) void ln_kernel(
    const float* __restrict__ X, float* __restrict__ Y,
    const float* __restrict__ g, const float* __restrict__ b,
    int Dd, int affine_relu) {
    const int row = blockIdx.x;
    const float* p = X + (size_t)row * Dd;
    float* q = Y + (size_t)row * Dd;
    __shared__ float red[4];
    const int lane = threadIdx.x & 63, wv = threadIdx.x >> 6;
    float lsum = 0.f;
    for (int j = threadIdx.x; j < Dd; j += 256) lsum += p[j];
    for (int off = 32; off; off >>= 1) lsum += __shfl_down(lsum, off);
    if (lane == 0) red[wv] = lsum;
    __syncthreads();
    const float mu = (red[0] + red[1] + red[2] + red[3]) / (float)Dd;
    __syncthreads();
    float lvar = 0.f;
    for (int j = threadIdx.x; j < Dd; j += 256) { float d = p[j] - mu; lvar += d * d; }
    for (int off = 32; off; off >>= 1) lvar += __shfl_down(lvar, off);
    if (lane == 0) red[wv] = lvar;
    __syncthreads();
    const float inv = rsqrtf((red[0] + red[1] + red[2] + red[3]) / (float)Dd + EPSV);
    for (int j = threadIdx.x; j < Dd; j += 256) {
        float xn = (p[j] - mu) * inv;
        if (affine_relu) xn = fmaxf(xn * g[j] + b[j], 0.0f);
        q[j] = xn;
    }
}

// ---------------- row squared norms of cb (one wave per row) ----------------
__global__ __launch_bounds__(256) void rownorm_kernel(
    const float* __restrict__ X, float* __restrict__ out, int rows, int Dd) {
    const int wv = threadIdx.x >> 6, lane = threadIdx.x & 63;
    const int row = blockIdx.x * 4 + wv;
    if (row >= rows) return;
    const float* p = X + (size_t)row * Dd;
    float s = 0.f;
    for (int j = lane; j < Dd; j += 64) { float v = p[j]; s += v * v; }
    for (int off = 32; off; off >>= 1) s += __shfl_down(s, off);
    if (lane == 0) out[row] = s;
}

// ---------------- rsn[r] = || recurrence_l(x[r]) * scale_l ||^2 ----------------
__global__ __launch_bounds__(256) void rsnorm_kernel(
    const float* __restrict__ X, const float* __restrict__ scales,
    const int* __restrict__ flags, int l, float* __restrict__ outn, int Dd) {
    if (flags[l]) return;
    const int wv = threadIdx.x >> 6, lane = threadIdx.x & 63;
    const int row = blockIdx.x * 4 + wv;
    float s_arr[8];
    for (int j = 0; j <= l; ++j) s_arr[j] = scales[j];
    const float* p = X + (size_t)row * Dd;
    float s = 0.f;
    for (int j = lane; j < Dd; j += 64) {
        float r_ = p[j];
        for (int q = 0; q < l; ++q) { float sc = s_arr[q]; float rv = r_ * sc; r_ -= rv / sc; }
        r_ *= s_arr[l];
        s += r_ * r_;
    }
    for (int off = 32; off; off >>= 1) s += __shfl_down(s, off);
    if (lane == 0) outn[row] = s;
}

// ---------------- qsum (elementwise, general recurrence) ----------------
__global__ void qsum_kernel(const float* __restrict__ X, const float* __restrict__ scales,
                            int L, float* __restrict__ Q, int n) {
    const int i = blockIdx.x * 256 + threadIdx.x;
    if (i >= n) return;
    float r = X[i], q = 0.f;
    for (int l = 0; l < L; ++l) {
        float s = scales[l];
        float rsv = r * s;
        q += rsv;
        r = r - rsv / s;
    }
    Q[i] = q;
}

extern "C" void kernel_launch(void* const* d_in, const int* in_sizes, int n_in,
                              void* d_out, int out_size, void* d_ws, size_t ws_size,
                              hipStream_t stream) {
    const float* features = (const float*)d_in[0];
    const float* W        = (const float*)d_in[1];
    const float* bproj    = (const float*)d_in[2];
    const float* lng      = (const float*)d_in[3];
    const float* lnb      = (const float*)d_in[4];
    const float* cb       = (const float*)d_in[5];
    const float* scales   = (const float*)d_in[6];
    const float* temp     = (const float*)d_in[7];

    const int D = in_sizes[2];            // 512
    const int M = in_sizes[0] / D;        // 8192
    const int L = in_sizes[6];            // 4
    const int K = in_sizes[5] / (L * D);  // 2048

    float* out    = (float*)d_out;                 // [M, L, K]
    float* out_ln = out + (size_t)M * L * K;       // [M, D]

    // workspace (floats): x[M*D] | y[M*D] (also qsum) | P1 (Fp then rsp, M*D bf16)
    //                     | Wp (D*D bf16) | cbp (K*D bf16) | rsn[M] | cn[L*K] | flags
    float* ws = (float*)d_ws;
    float* x  = ws;
    float* y  = x + (size_t)M * D;
    short* P1 = (short*)(y + (size_t)M * D);
    float* aP1 = y + (size_t)M * D + (size_t)M * D / 2;
    short* Wp = (short*)aP1;
    float* aWp = aP1 + (size_t)D * D / 2;
    short* cbp = (short*)aWp;
    float* rsn = aWp + (size_t)K * D / 2;
    float* cn  = rsn + M;
    int* flags = (int*)(cn + (size_t)L * K);

    flags_kernel<<<1, 64, 0, stream>>>(scales, L, flags);

    // pack W and features to bf16 [k/8][row][8]
    pack_kernel<<<D / 32, 256, 0, stream>>>(W, Wp, D, nullptr, nullptr, 0, 0);
    pack_kernel<<<M / 32, 256, 0, stream>>>(features, P1, M, nullptr, nullptr, 0, 0);

    // y = features @ W^T + b ; x = relu(LN(y)*g + b)
    gemm1_mfma<<<dim3(M / 128, D / 128), 256, 0, stream>>>(P1, Wp, bproj, y, M, D, D);
    ln_kernel<<<M, 256, 0, stream>>>(y, x, lng, lnb, D, 1);

    // quantized_sum = LN(qsum) (no affine); reuse y for qsum
    qsum_kernel<<<(M * D + 255) / 256, 256, 0, stream>>>(x, scales, L, y, M * D);
    ln_kernel<<<M, 256, 0, stream>>>(y, out_ln, nullptr, nullptr, D, 0);

    // codebook row norms
    rownorm_kernel<<<(L * K + 3) / 4, 256, 0, stream>>>(cb, cn, L * K, D);

    // per-level logits
    dim3 gd(M / 128, K / 128);
    for (int l = 0; l < L; ++l) {
        pack_kernel<<<K / 32, 256, 0, stream>>>(cb + (size_t)l * K * D, cbp, K, nullptr, flags, l, 0);
        pack_kernel<<<M / 32, 256, 0, stream>>>(x, P1, M, scales, flags, l, 1);
        rsnorm_kernel<<<M / 4, 256, 0, stream>>>(x, scales, flags, l, rsn, D);
        dist_mfma<<<gd, 256, 0, stream>>>(P1, cbp, rsn, cn + (size_t)l * K, temp, flags, l,
                                          out + (size_t)l * K, M, K, D, L * K);
    }
}